// Round 1
// 98.306 us; speedup vs baseline: 1.0474x; 1.0474x over previous
//
#include <hip/hip_runtime.h>

// INRF fused:  out[b,ij,c] = sum_pq [ M2[ij,pq]*x[b,pq,c] - W2[ij,pq]*relu(x[b,pq,c] - S[b,pq,ij,c]) ]
//   S[b,pq,ij,f] = sum_{k=(dh,dw,c)} patch(x)[b,pq,k] * G[ij,k,f]   (3x3 SAME conv, K=144->pad 160)
// Phase 1 (build_A): im2col -> bf16 A (4096x160, MFMA-frag-swizzled) in d_ws, PLUS
//   Xf = x pre-gathered in C-fragment layout (float4 per (tile,lane)).
//   One thread per (row, tap, half) unit -> 320/384 blocks (was 16 blocks = latency-bound).
// Phase 2 (inrf_main): 256 blocks x 512 thr, 4 ij per block, MFMA GEMM + fused epilogue.
//   B-frags read straight from global (no G_l staging: was 36KB dead LDS + 4-way bank
//   conflicts at init). Main loop hand-unrolled x2 ping-pong (kills 24 reg copies/iter).

typedef __attribute__((ext_vector_type(8))) short bf16x8;
typedef __attribute__((ext_vector_type(4))) float f32x4;

__device__ inline unsigned short f2bf(float x) {
    unsigned u = __float_as_uint(x);
    u += 0x7FFFu + ((u >> 16) & 1u);          // round-to-nearest-even
    return (unsigned short)(u >> 16);
}
__device__ inline unsigned pack2(float a, float b) {
    return (unsigned)f2bf(a) | ((unsigned)f2bf(b) << 16);
}

// ---------------- Phase 1 ----------------
// unit u = tid>>12:
//   u in [0,18): tap = u>>1, h = u&1 -> one uint4 (8 bf16 ch) at quad=(tap&1)*2+h, kk=tap>>1
//   u == 18,19 : zero-pad kk=4, quads 2,3
//   u >= 20 (XF only): Xf C-frag gather, one float4 per (tile, lane)
template<bool XF>
__global__ __launch_bounds__(256) void build_A(const float* __restrict__ inp,
                                               uint4* __restrict__ A,
                                               float4* __restrict__ Xf) {
    const int tid = blockIdx.x * 256 + threadIdx.x;
    const int u = tid >> 12;
    if (XF && u >= 20) {
        const int idx = tid - 81920;          // 0..16383
        const int tile = idx >> 6;
        const int ll = idx & 63;
        const int rowb = tile * 16 + (ll >> 4) * 4;
        const int col = ll & 15;
        float4 v;
        v.x = inp[(rowb + 0) * 16 + col];
        v.y = inp[(rowb + 1) * 16 + col];
        v.z = inp[(rowb + 2) * 16 + col];
        v.w = inp[(rowb + 3) * 16 + col];
        Xf[idx] = v;
        return;
    }
    const int row = tid & 4095;
    const int tile = row >> 4, m = row & 15;
    if (u >= 18) {                            // zero-pad k=144..159 (kk=4, quads 2,3)
        const uint4 z = {0, 0, 0, 0};
        A[(tile * 5 + 4) * 64 + (u - 16) * 16 + m] = z;
        return;
    }
    const int tap = u >> 1, h = u & 1;
    const int dh = tap / 3, dw = tap - dh * 3;
    const int b = row >> 10, pq = row & 1023;
    const int p = pq >> 5, q = pq & 31;
    const int pp = p + dh - 1, qq = q + dw - 1;
    const int kk = tap >> 1, quad = (tap & 1) * 2 + h;
    uint4 o = {0, 0, 0, 0};
    if (((unsigned)pp < 32u) && ((unsigned)qq < 32u)) {
        const float4* s = (const float4*)(inp + b * 16384 + (pp * 32 + qq) * 16 + 8 * h);
        const float4 f0 = s[0], f1 = s[1];
        o.x = pack2(f0.x, f0.y); o.y = pack2(f0.z, f0.w);
        o.z = pack2(f1.x, f1.y); o.w = pack2(f1.z, f1.w);
    }
    A[(tile * 5 + kk) * 64 + quad * 16 + m] = o;
}

// ---------------- Phase 2 ----------------
template<bool XF>
__global__ __launch_bounds__(512, 2) void inrf_main(
    const float* __restrict__ inp,   // (4,1024,16)
    const float* __restrict__ M,     // rows of 1024 per ij
    const float* __restrict__ Wp,    // rows of 1024 per ij
    const float* __restrict__ G,     // 2304 per ij
    const uint4* __restrict__ Aw,    // swizzled bf16 patches
    const float4* __restrict__ Xf,   // x in C-frag layout (XF only)
    float* __restrict__ out)         // (4,1024,16)
{
    const int bid = blockIdx.x;      // ij block: handles ij = bid*4 .. bid*4+3
    const int t = threadIdx.x;

    __shared__ __align__(16) float W2l[4096];
    __shared__ __align__(16) float M2l[4096];
    __shared__ float red[8][64];

    {
        const float* Wg = Wp + bid * 4096;
        const float* Mg = M  + bid * 4096;
#pragma unroll
        for (int i = 0; i < 8; ++i) {
            W2l[t + i * 512] = Wg[t + i * 512];
            M2l[t + i * 512] = Mg[t + i * 512];
        }
    }

    const int l = t & 63, w = t >> 6;      // 8 waves
    const int quad = l >> 4, col = l & 15;
    const int b = w >> 1;                  // 2 waves per batch element

    // B fragments straight from global: lane holds G[k=kk*32+quad*8+j][f=col], bf16.
    // Per-instr 64 distinct floats (no redundancy); 8-wave redundancy is L1/L2-absorbed.
    const float* Gg = G + bid * 9216;
    bf16x8 Bf[4][5];
#pragma unroll
    for (int ij = 0; ij < 4; ++ij) {
#pragma unroll
        for (int kk = 0; kk < 5; ++kk) {
            bf16x8 f;
#pragma unroll
            for (int j = 0; j < 8; ++j) {
                const int k = kk * 32 + quad * 8 + j;
                const float v = (k < 144) ? Gg[ij * 2304 + k * 16 + col] : 0.f;
                f[j] = (short)f2bf(v);
            }
            Bf[ij][kk] = f;
        }
    }

    __syncthreads();                       // W2l/M2l ready before first epilogue

    const int tile0 = b * 64 + (w & 1) * 32;   // 32 tiles per wave
    const float* inb = inp + b * 16384;
    (void)inb;

    float accv[4] = {0.f, 0.f, 0.f, 0.f};

    uint4 A0[5], A1[5];
    float4 v0, v1;

    auto prefetch = [&](uint4 (&Ar)[5], float4& vr, int tn) {
#pragma unroll
        for (int kk = 0; kk < 5; ++kk) Ar[kk] = Aw[(tn * 5 + kk) * 64 + l];
        if (XF) {
            vr = Xf[tn * 64 + l];
        } else {
            const int pqb = (tn & 63) * 16 + quad * 4;
            vr.x = inb[(pqb + 0) * 16 + col];
            vr.y = inb[(pqb + 1) * 16 + col];
            vr.z = inb[(pqb + 2) * 16 + col];
            vr.w = inb[(pqb + 3) * 16 + col];
        }
    };

    auto compute = [&](const uint4 (&Ar)[5], const float4& vr, int tg) {
        f32x4 C[4];
#pragma unroll
        for (int ij = 0; ij < 4; ++ij) C[ij] = (f32x4){0.f, 0.f, 0.f, 0.f};
#pragma unroll
        for (int kk = 0; kk < 5; ++kk) {
            const bf16x8 a = __builtin_bit_cast(bf16x8, Ar[kk]);
#pragma unroll
            for (int ij = 0; ij < 4; ++ij)
                C[ij] = __builtin_amdgcn_mfma_f32_16x16x32_bf16(a, Bf[ij][kk], C[ij], 0, 0, 0);
        }
        // fused epilogue: acc += M2*x - W2*relu(x - S); rows pqb..pqb+3, col c
        const int pqb = (tg & 63) * 16 + quad * 4;
#pragma unroll
        for (int ij = 0; ij < 4; ++ij) {
            const float4 w2 = *(const float4*)&W2l[ij * 1024 + pqb];
            const float4 m2 = *(const float4*)&M2l[ij * 1024 + pqb];
            accv[ij] += m2.x * vr.x - w2.x * fmaxf(vr.x - C[ij][0], 0.f);
            accv[ij] += m2.y * vr.y - w2.y * fmaxf(vr.y - C[ij][1], 0.f);
            accv[ij] += m2.z * vr.z - w2.z * fmaxf(vr.z - C[ij][2], 0.f);
            accv[ij] += m2.w * vr.w - w2.w * fmaxf(vr.w - C[ij][3], 0.f);
        }
    };

    prefetch(A0, v0, tile0);
#pragma unroll 1
    for (int i = 0; i < 32; i += 2) {
        prefetch(A1, v1, tile0 + i + 1);
        compute(A0, v0, tile0 + i);
        if (i + 2 < 32) prefetch(A0, v0, tile0 + i + 2);
        compute(A1, v1, tile0 + i + 1);
    }

    // reduce over quads (rows) -> per-wave totals for (ij, col)
#pragma unroll
    for (int ij = 0; ij < 4; ++ij) {
        float v = accv[ij];
        v += __shfl_xor(v, 16);
        v += __shfl_xor(v, 32);
        if (l < 16) red[w][ij * 16 + l] = v;
    }
    __syncthreads();

    if (t < 256) {
        const int ob = t >> 6, oij = (t >> 4) & 3, oc = t & 15;
        const float r0 = red[ob * 2][oij * 16 + oc] + red[ob * 2 + 1][oij * 16 + oc];
        out[ob * 16384 + (bid * 4 + oij) * 16 + oc] = r0;   // L = 1
    }
}

extern "C" void kernel_launch(void* const* d_in, const int* in_sizes, int n_in,
                              void* d_out, int out_size, void* d_ws, size_t ws_size,
                              hipStream_t stream) {
    const float* inp = (const float*)d_in[0];   // 65536
    const float* M   = (const float*)d_in[1];   // 1048576
    const float* Wp  = (const float*)d_in[2];   // 1048576
    const float* G   = (const float*)d_in[3];   // 2359296
    float* out = (float*)d_out;

    uint4*  A  = (uint4*)d_ws;                                   // 81920*16B = 1.31 MB
    float4* Xf = (float4*)((char*)d_ws + 81920 * sizeof(uint4)); // +256 KB
    const size_t need = 81920 * sizeof(uint4) + 16384 * sizeof(float4);

    if (ws_size >= need) {
        build_A<true><<<dim3(384), dim3(256), 0, stream>>>(inp, A, Xf);
        inrf_main<true><<<dim3(256), dim3(512), 0, stream>>>(inp, M, Wp, G, A, Xf, out);
    } else {
        build_A<false><<<dim3(320), dim3(256), 0, stream>>>(inp, A, nullptr);
        inrf_main<false><<<dim3(256), dim3(512), 0, stream>>>(inp, M, Wp, G, A, nullptr, out);
    }
}